// Round 6
// baseline (416.952 us; speedup 1.0000x reference)
//
#include <hip/hip_runtime.h>

// out[e] = concat(node_states[src[e]], node_states[tgt[e]])
// v6: XCD row-partitioned gather (L2-residency experiment).
//
// Evidence: v1..v5 (MLP depth, EPW 8/16, pipelining, store policy, scalar
// index path) all cluster at kernel ~125-155 us = combined 5.2 TB/s ~ 83%
// of the demonstrated 6.3 TB/s -> mixed-stream HBM ceiling IF the gathers
// miss to HBM. Premise: 328 MB/iter NT write stream wipes the 256 MB L3,
// and the 5.12 MB table thrashes the 4 MiB per-XCD L2 -> gathers hit HBM.
//
// Fix under test: split rows at 5000. Blocks with blockIdx%8 in {0..3}
// (XCDs 0-3 under measured round-robin dispatch) own rows <5000; residues
// {4..7} own rows >=5000. Both sides scan all edges; each gathers/stores
// only the 512 B output halves whose row it owns (per-half predication,
// no overlap, exact coverage independent of the actual XCD mapping ->
// correctness never depends on dispatch; only locality does).
// Per-XCD working set: 2.56 MB table slice + ~0.7 MB index stream < 4 MiB.
//
// Structure otherwise = v2/v5 winner: one-shot waves, EPW=8, batched
// independent gathers, NT stores (A/B winner over plain).

typedef float v4f __attribute__((ext_vector_type(4)));

#define EPW 8          // edges per wave
#define ROW_SPLIT 5000 // N_NODES / 2

__global__ __launch_bounds__(256) void NodePropagator_75110388073048_kernel(
    const v4f* __restrict__ ns,       // node_states as [N, 32] v4f
    const int* __restrict__ src32,    // edge_sources (int32 word view)
    const int* __restrict__ tgt32,    // edge_targets (int32 word view)
    v4f* __restrict__ out,            // [E, 64] v4f
    int nEdges, int nGroups)
{
    int lane = threadIdx.x & 63;
    int wIn  = threadIdx.x >> 6;          // wave within block (0..3)
    int b    = blockIdx.x;

    int side     = (b & 7) >> 2;          // 0: rows <5000, 1: rows >=5000
    int idxInGrp = (b >> 3) * 4 + (b & 3);
    int wg       = idxInGrp * 4 + wIn;    // wave-group id within this side
    if (wg >= nGroups) return;
    int e0 = wg * EPW;

    int half = lane >> 5;                 // 0 = source half, 1 = target half
    int c    = lane & 31;                 // v4f chunk within the half

    // --- index dtype probe (int64 vs int32), uniform cached loads ---
    // Reference emits int64 (values < 10000 -> high words 0). For genuine
    // int32 data, 4 random values in [0,10000) all being 0 is ~1e-16.
    bool is_i64 = (src32[1] == 0) & (src32[3] == 0) &
                  (src32[5] == 0) & (src32[7] == 0);
    int stride = is_i64 ? 2 : 1;          // int32 words per index element

    const int* idxp = half ? tgt32 : src32;

    // Batch 1: index loads (low word), clamped; stores guarded below.
    int rows[EPW];
    bool own[EPW];
#pragma unroll
    for (int k = 0; k < EPW; ++k) {
        int e = e0 + k;
        if (e >= nEdges) e = nEdges - 1;
        rows[k] = idxp[e * stride];
        // side 0 owns row < ROW_SPLIT, side 1 owns row >= ROW_SPLIT.
        own[k] = (rows[k] < ROW_SPLIT) == (side == 0);
    }

    // Batch 2: independent gathers, predicated per 32-lane half so each
    // side only touches its own 2.56 MB table slice (L2-resident).
    v4f v[EPW];
#pragma unroll
    for (int k = 0; k < EPW; ++k) {
        if (own[k]) v[k] = ns[rows[k] * 32 + c];
    }

    // Batch 3: NT streaming stores, same predicate (exact disjoint coverage
    // between the two sides).
#pragma unroll
    for (int k = 0; k < EPW; ++k) {
        int e = e0 + k;
        if (own[k] && e < nEdges)
            __builtin_nontemporal_store(v[k], &out[e * 64 + lane]);
    }
}

extern "C" void kernel_launch(void* const* d_in, const int* in_sizes, int n_in,
                              void* d_out, int out_size, void* d_ws, size_t ws_size,
                              hipStream_t stream) {
    const v4f* ns  = (const v4f*)d_in[0];
    const int* src = (const int*)d_in[1];
    const int* tgt = (const int*)d_in[2];
    v4f*       out = (v4f*)d_out;

    int nEdges  = in_sizes[1];                        // 320000
    int nGroups = (nEdges + EPW - 1) / EPW;           // 40000 wave-groups/side

    int block = 256;                                  // 4 waves/block
    int blocksPerSide = (nGroups + 3) / 4;            // 10000
    int oct  = (blocksPerSide + 3) / 4;               // groups of 4 residues
    int grid = oct * 8;                               // 20000 (both sides)

    NodePropagator_75110388073048_kernel<<<grid, block, 0, stream>>>(
        ns, src, tgt, out, nEdges, nGroups);
}